// Round 9
// baseline (137.582 us; speedup 1.0000x reference)
//
#include <hip/hip_runtime.h>
#include <stdint.h>

#define B_N   4096
#define D_DIM 1024
#define INF_F 3.4e38f
#define NT    64                    // 64x64 tiles
#define NBLK  (NT * (NT + 1) / 2)   // 2080

typedef float floatx4 __attribute__((ext_vector_type(4)));

// ws layout (bytes):
//   [0]      u64   minpack[4096]
//   [32768]  u32   maxbits[4096]
//   [49152]  f32   norms[4096]
//   [65600]  i32   ref_idx[4096]
//   [131072] fp8   xq[4096*1024]  (4 MB)
#define XQ_OFF 131072

// One block per row: cast to fp8 e4m3 (HW RNE), fp32-exact row sum-of-squares,
// init minpack/maxbits.
__global__ __launch_bounds__(256)
void k_prep(const float* __restrict__ x, unsigned char* __restrict__ xq,
            float* __restrict__ norms,
            unsigned long long* __restrict__ minpack,
            unsigned int* __restrict__ maxbits) {
    const int row = blockIdx.x;
    const int t   = threadIdx.x;
    float4 v = ((const float4*)x)[row * 256 + t];
    int p = __builtin_amdgcn_cvt_pk_fp8_f32(v.x, v.y, 0, false);
    p     = __builtin_amdgcn_cvt_pk_fp8_f32(v.z, v.w, p, true);
    ((int*)xq)[row * 256 + t] = p;
    float s = v.x * v.x + v.y * v.y + v.z * v.z + v.w * v.w;
    #pragma unroll
    for (int off = 32; off; off >>= 1) s += __shfl_down(s, off);
    __shared__ float ws4[4];
    if ((t & 63) == 0) ws4[t >> 6] = s;
    __syncthreads();
    if (t == 0) {
        norms[row]   = ws4[0] + ws4[1] + ws4[2] + ws4[3];
        minpack[row] = 0xFFFFFFFFFFFFFFFFull;
        maxbits[row] = 0u;
    }
}

#define GLDS(g, l)                                                              \
    __builtin_amdgcn_global_load_lds(                                           \
        (__attribute__((address_space(1))) void*)(void*)(g),                    \
        (__attribute__((address_space(3))) void*)(void*)(l), 16, 0, 0)

// 64x64-tile fp8 MFMA Gram pass, 2 waves/block with the K-range split between
// waves (wave w: k in [512w, 512w+512)). Per-wave PRIVATE 3-buffer LDS ring,
// depth-2 GLDS prefetch, fine-grained s_waitcnt vmcnt(16/8/0) — never a full
// drain mid-loop, zero s_barrier in the K-loop (AITER-style pipeline).
// Ring-3 reuse is safe: batch it+2 is issued only after iteration it-1's
// MFMAs issued, and the compiler's register-dependency lgkmcnt waits ensure
// those ds_reads completed before the MFMAs issued.
// LDS row = 64 B = 4 slots x 16 B, stored slot = slot ^ (row & 3): GLDS keeps
// base+lane*16 contiguity; ds_read_b64 frags land uniform 4 lanes/bank.
__global__ __launch_bounds__(128, 1)
void k_pass1(const unsigned char* __restrict__ xq,
             const float* __restrict__ norms,
             unsigned long long* __restrict__ minpack,
             unsigned int* __restrict__ maxbits) {
    // linear block id -> (ti, tj), tj <= ti
    int bid = blockIdx.x;
    int ti  = (int)((sqrtf(8.f * bid + 1.f) - 1.f) * 0.5f);
    while ((ti + 1) * (ti + 2) / 2 <= bid) ti++;
    while (ti * (ti + 1) / 2 > bid) ti--;
    int tj  = bid - ti * (ti + 1) / 2;

    __shared__ __align__(16) unsigned char lds[49152]; // 2 waves x 3 x (A4K+B4K)

    const int t    = threadIdx.x;
    const int w    = t >> 6, lane = t & 63;
    const int q4   = lane >> 4, c15 = lane & 15;
    const int i0   = ti * 64, j0 = tj * 64;

    unsigned char* bufA[3]; unsigned char* bufB[3];
    #pragma unroll
    for (int b = 0; b < 3; b++) {
        bufA[b] = lds + w * 24576 + b * 8192;
        bufB[b] = bufA[b] + 4096;
    }

    // staging decode: lane -> row-in-instr sr = lane>>2, stored slot lane&3,
    // global chunk c = (lane&3) ^ (sr&3)
    const int sr = lane >> 2;
    const int sc = (lane & 3) ^ (sr & 3);

    const unsigned char* gA[4]; const unsigned char* gB[4];
    #pragma unroll
    for (int e = 0; e < 4; e++) {
        int row = e * 16 + sr;
        size_t ko = (size_t)w * 512 + (size_t)sc * 16;
        gA[e] = xq + (size_t)(i0 + row) * D_DIM + ko;
        gB[e] = xq + (size_t)(j0 + row) * D_DIM + ko;
    }

#define ISSUE_BATCH(bslot, itk)                                                 \
    do {                                                                        \
        unsigned char* A_ = bufA[(bslot)];                                      \
        unsigned char* B_ = bufB[(bslot)];                                      \
        _Pragma("unroll")                                                       \
        for (int e = 0; e < 4; e++) {                                           \
            GLDS(gA[e] + (itk) * 64, A_ + e * 1024);                            \
            GLDS(gB[e] + (itk) * 64, B_ + e * 1024);                            \
        }                                                                       \
    } while (0)

    // fragment offsets: row r = st*16+c15 (r&3 == c15&3), byte b = kk*32+q4*8
    // slot sl = kk*2+(q4>>1), stored = sl^(r&3), +8 if q4 odd
    int foff[4][2];
    #pragma unroll
    for (int st = 0; st < 4; st++)
        #pragma unroll
        for (int kk = 0; kk < 2; kk++)
            foff[st][kk] = (st * 16 + c15) * 64 +
                           ((((kk << 1) | (q4 >> 1)) ^ (c15 & 3)) << 4) +
                           ((q4 & 1) << 3);

    floatx4 acc[4][4];
    #pragma unroll
    for (int m = 0; m < 4; m++)
        #pragma unroll
        for (int n = 0; n < 4; n++)
            acc[m][n] = (floatx4){0.f, 0.f, 0.f, 0.f};

    ISSUE_BATCH(0, 0);
    ISSUE_BATCH(1, 1);

    #pragma unroll
    for (int it = 0; it < 8; it++) {         // per-wave K = 512, BK = 64
        if (it + 2 < 8) ISSUE_BATCH((it + 2) % 3, it + 2);
        // wait for the OLDEST batch (8 loads) only; newer batches stay in flight
        if (it < 6)      asm volatile("s_waitcnt vmcnt(16)" ::: "memory");
        else if (it == 6) asm volatile("s_waitcnt vmcnt(8)" ::: "memory");
        else              asm volatile("s_waitcnt vmcnt(0)" ::: "memory");
        const unsigned char* myA = bufA[it % 3];
        const unsigned char* myB = bufB[it % 3];
        #pragma unroll
        for (int kk = 0; kk < 2; kk++) {
            long long af[4], bfr[4];
            #pragma unroll
            for (int st = 0; st < 4; st++) {
                af[st]  = *(const long long*)(myA + foff[st][kk]);
                bfr[st] = *(const long long*)(myB + foff[st][kk]);
            }
            #pragma unroll
            for (int m = 0; m < 4; m++)
                #pragma unroll
                for (int n = 0; n < 4; n++)
                    acc[m][n] = __builtin_amdgcn_mfma_f32_16x16x32_fp8_fp8(
                        af[m], bfr[n], acc[m][n], 0, 0, 0);
        }
    }

    // combine the two K-halves through LDS (reuse staging space)
    __syncthreads();
    float* cbuf = (float*)lds;
    if (w == 1) {
        #pragma unroll
        for (int m = 0; m < 4; m++)
            #pragma unroll
            for (int n = 0; n < 4; n++)
                #pragma unroll
                for (int r = 0; r < 4; r++)
                    cbuf[((m * 4 + n) * 4 + r) * 64 + lane] = acc[m][n][r];
    }
    __syncthreads();
    if (w == 0) {
        #pragma unroll
        for (int m = 0; m < 4; m++)
            #pragma unroll
            for (int n = 0; n < 4; n++)
                #pragma unroll
                for (int r = 0; r < 4; r++)
                    acc[m][n][r] += cbuf[((m * 4 + n) * 4 + r) * 64 + lane];

        // epilogue: d = sqrt(ni+nj-2dot), strictly j<i; row min-pack + max
        float njv[4];
        #pragma unroll
        for (int n = 0; n < 4; n++) njv[n] = norms[j0 + n * 16 + c15];
        #pragma unroll
        for (int m = 0; m < 4; m++) {
            #pragma unroll
            for (int r = 0; r < 4; r++) {
                int gi   = i0 + m * 16 + q4 * 4 + r;
                float ni = norms[gi];
                unsigned long long mp = 0xFFFFFFFFFFFFFFFFull;
                float mx = -INF_F;
                #pragma unroll
                for (int n = 0; n < 4; n++) {
                    int gj = j0 + n * 16 + c15;
                    if (gj < gi) {
                        float d = sqrtf(fmaxf(ni + njv[n] - 2.f * acc[m][n][r], 0.f));
                        unsigned long long p =
                            ((unsigned long long)__float_as_uint(d) << 32) | (unsigned)gj;
                        if (p < mp) mp = p;
                        mx = fmaxf(mx, d);
                    }
                }
                #pragma unroll
                for (int off = 1; off < 16; off <<= 1) {
                    unsigned long long op = __shfl_xor(mp, off, 64);
                    if (op < mp) mp = op;
                    float om = __shfl_xor(mx, off, 64);
                    mx = fmaxf(mx, om);
                }
                if (c15 == 0 && mp != 0xFFFFFFFFFFFFFFFFull) {
                    atomicMin(&minpack[gi], mp);
                    atomicMax(&maxbits[gi], __float_as_uint(mx));
                }
            }
        }
    }
}

// Fused: verify all-insert (prefix min/max scan), fast-path outputs, exact
// sequential continuation only if verification failed. One block, 1024 threads.
__global__ __launch_bounds__(1024)
void k_tail(const unsigned long long* __restrict__ minpack,
            const unsigned int* __restrict__ maxbits,
            const float* __restrict__ x, const float* __restrict__ norms,
            const int* __restrict__ labels, int* __restrict__ ref_idx,
            float* __restrict__ out) {
    const int t = threadIdx.x;
    float m[4], M[4];
    #pragma unroll
    for (int q = 0; q < 4; q++) {
        int i = t * 4 + q;
        unsigned long long p = minpack[i];
        float dmin = (p == 0xFFFFFFFFFFFFFFFFull)
                       ? INF_F : __uint_as_float((unsigned)(p >> 32));
        m[q] = (i == 0) ? INF_F : dmin;
        M[q] = (i == 0) ? -INF_F : __uint_as_float(maxbits[i]);
    }
    float pmin[4], pmax[4];
    pmin[0] = m[0]; pmax[0] = M[0];
    #pragma unroll
    for (int q = 1; q < 4; q++) {
        pmin[q] = fminf(pmin[q - 1], m[q]);
        pmax[q] = fmaxf(pmax[q - 1], M[q]);
    }
    __shared__ float smin[1024], smax[1024];
    smin[t] = pmin[3]; smax[t] = pmax[3];
    __syncthreads();
    for (int off = 1; off < 1024; off <<= 1) {
        float a = (t >= off) ? smin[t - off] : INF_F;
        float b = (t >= off) ? smax[t - off] : -INF_F;
        __syncthreads();
        smin[t] = fminf(smin[t], a);
        smax[t] = fmaxf(smax[t], b);
        __syncthreads();
    }
    float exMin = (t > 0) ? smin[t - 1] : INF_F;
    float exMax = (t > 0) ? smax[t - 1] : -INF_F;

    int viol = B_N;
    #pragma unroll
    for (int q = 0; q < 4; q++) {
        int i = t * 4 + q;
        if (i >= 1) {
            float pm = (q == 0) ? exMin : fminf(exMin, pmin[q - 1]);
            float pM = (q == 0) ? exMax : fmaxf(exMax, pmax[q - 1]);
            float R  = (i == 1) ? 1.0f : (pm + pM) / 3.0f;
            if (!(m[q] > R) && i < viol) viol = i;
        }
    }
    __shared__ int sv[1024];
    sv[t] = viol;
    __syncthreads();
    for (int off = 512; off; off >>= 1) {
        if (t < off) sv[t] = min(sv[t], sv[t + off]);
        __syncthreads();
    }
    const int s_star = sv[0];

    for (int i = t; i < s_star; i += 1024) out[i] = (float)labels[i];

    __shared__ float s_state[3];
    __shared__ int s_n;
    if (s_star < B_N && t == (s_star >> 2)) {
        int q = s_star & 3;
        float pm = (q == 0) ? exMin : fminf(exMin, pmin[q - 1]);
        float pM = (q == 0) ? exMax : fmaxf(exMax, pmax[q - 1]);
        float md = fminf(pm, m[q]);
        float Md = fmaxf(pM, M[q]);
        s_state[0] = md; s_state[1] = Md; s_state[2] = (md + Md) / 3.0f;
        s_n = s_star;
        unsigned long long p = minpack[s_star];
        int j = (int)(unsigned)(p & 0xFFFFFFFFu);
        out[s_star] = (float)labels[j];
    }
    if (s_star >= B_N) return;

    for (int s = t; s < s_star; s += 1024) ref_idx[s] = s;
    __syncthreads();

    __shared__ unsigned long long redp[1024];
    __shared__ float redm[1024];
    for (int i = s_star + 1; i < B_N; i++) {
        int n = s_n;
        const float* xi = x + (size_t)i * D_DIM;
        float ni = norms[i];
        unsigned long long mp = 0xFFFFFFFFFFFFFFFFull;
        float mx = -INF_F;
        for (int slot = t; slot < n; slot += 1024) {
            int j = ref_idx[slot];
            const float* xj = x + (size_t)j * D_DIM;
            float dot = 0.f;
            for (int k = 0; k < D_DIM; k++) dot = fmaf(xi[k], xj[k], dot);
            float d = sqrtf(fmaxf(ni + norms[j] - 2.f * dot, 0.f));
            unsigned long long p =
                ((unsigned long long)__float_as_uint(d) << 32) | (unsigned)slot;
            if (p < mp) mp = p;
            mx = fmaxf(mx, d);
        }
        redp[t] = mp; redm[t] = mx;
        __syncthreads();
        for (int off = 512; off; off >>= 1) {
            if (t < off) {
                if (redp[t + off] < redp[t]) redp[t] = redp[t + off];
                redm[t] = fmaxf(redm[t], redm[t + off]);
            }
            __syncthreads();
        }
        if (t == 0) {
            unsigned long long p = redp[0];
            float min_act = __uint_as_float((unsigned)(p >> 32));
            int minslot   = (int)(unsigned)(p & 0xFFFFFFFFu);
            float max_act = redm[0];
            bool insert = (min_act > s_state[2]);
            int pred;
            if (insert) {
                ref_idx[n] = i;
                s_n = n + 1;
                pred = (min_act <= 0.0f) ? labels[ref_idx[minslot]] : labels[i];
            } else {
                pred = labels[ref_idx[minslot]];
            }
            float md = fminf(s_state[0], min_act);
            float Md = fmaxf(s_state[1], max_act);
            s_state[0] = md; s_state[1] = Md; s_state[2] = (md + Md) / 3.0f;
            out[i] = (float)pred;
        }
        __syncthreads();
    }
}

extern "C" void kernel_launch(void* const* d_in, const int* in_sizes, int n_in,
                              void* d_out, int out_size, void* d_ws, size_t ws_size,
                              hipStream_t stream) {
    const float* x      = (const float*)d_in[0];
    const int*   labels = (const int*)d_in[1];
    float*       out    = (float*)d_out;
    char* ws = (char*)d_ws;
    unsigned long long* minpack = (unsigned long long*)ws;
    unsigned int*       maxbits = (unsigned int*)(ws + 32768);
    float*              norms   = (float*)(ws + 49152);
    int*                ref_idx = (int*)(ws + 65600);
    unsigned char*      xq      = (unsigned char*)(ws + XQ_OFF);

    k_prep<<<B_N, 256, 0, stream>>>(x, xq, norms, minpack, maxbits);
    k_pass1<<<NBLK, 128, 0, stream>>>(xq, norms, minpack, maxbits);
    k_tail<<<1, 1024, 0, stream>>>(minpack, maxbits, x, norms, labels, ref_idx, out);
}

// Round 10
// 109.356 us; speedup vs baseline: 1.2581x; 1.2581x over previous
//
#include <hip/hip_runtime.h>
#include <stdint.h>

#define B_N   4096
#define D_DIM 1024
#define INF_F 3.4e38f

typedef float floatx4 __attribute__((ext_vector_type(4)));

// ws layout (bytes):
//   [0]      u64   minpack[4096]
//   [32768]  u32   maxbits[4096]
//   [49152]  f32   norms[4096]
//   [65600]  i32   ref_idx[4096]
//   [131072] fp8   xq[4096*1024]  (4 MB)
#define XQ_OFF 131072

// One block per row: cast to fp8 e4m3 (HW RNE), fp32-exact row sum-of-squares,
// init minpack/maxbits.
__global__ __launch_bounds__(256)
void k_prep(const float* __restrict__ x, unsigned char* __restrict__ xq,
            float* __restrict__ norms,
            unsigned long long* __restrict__ minpack,
            unsigned int* __restrict__ maxbits) {
    const int row = blockIdx.x;
    const int t   = threadIdx.x;
    float4 v = ((const float4*)x)[row * 256 + t];
    int p = __builtin_amdgcn_cvt_pk_fp8_f32(v.x, v.y, 0, false);
    p     = __builtin_amdgcn_cvt_pk_fp8_f32(v.z, v.w, p, true);
    ((int*)xq)[row * 256 + t] = p;
    float s = v.x * v.x + v.y * v.y + v.z * v.z + v.w * v.w;
    #pragma unroll
    for (int off = 32; off; off >>= 1) s += __shfl_down(s, off);
    __shared__ float ws4[4];
    if ((t & 63) == 0) ws4[t >> 6] = s;
    __syncthreads();
    if (t == 0) {
        norms[row]   = ws4[0] + ws4[1] + ws4[2] + ws4[3];
        minpack[row] = 0xFFFFFFFFFFFFFFFFull;
        maxbits[row] = 0u;
    }
}

#define GLDS(g, l)                                                              \
    __builtin_amdgcn_global_load_lds(                                           \
        (__attribute__((address_space(1))) void*)(void*)(g),                    \
        (__attribute__((address_space(3))) void*)(void*)(l), 16, 0, 0)

// fp8 MFMA Gram pass, 128x128 tiles over the lower triangle, fused per-row
// min/argmin/max. DOUBLE-BUFFERED LDS, BK=64 fp8, ONE barrier per iteration:
// chunk it+1 is issued right after the barrier, consumed at the next barrier —
// so the compiler's mandatory `s_waitcnt vmcnt(0)` before `s_barrier` drains
// loads that had a full compute phase to land (vs R6's just-issued drain).
// Correctness relies only on that barrier drain (the R6-validated mechanism).
// LDS row = 64 B = 4 slots x 16 B, stored slot = slot ^ (row & 3): GLDS keeps
// its mandatory base+lane*16 contiguity (global side fetches the permuted
// chunk); ds_read_b64 fragments land uniform 4 accesses/bank (b64 minimum).
__global__ __launch_bounds__(256, 3)
void k_pass1_fp8(const unsigned char* __restrict__ xq,
                 const float* __restrict__ norms,
                 unsigned long long* __restrict__ minpack,
                 unsigned int* __restrict__ maxbits) {
    // linear block id -> (ti, tj), tj <= ti
    int bid = blockIdx.x;
    int ti  = (int)((sqrtf(8.f * bid + 1.f) - 1.f) * 0.5f);
    while ((ti + 1) * (ti + 2) / 2 <= bid) ti++;
    while (ti * (ti + 1) / 2 > bid) ti--;
    int tj  = bid - ti * (ti + 1) / 2;

    __shared__ __align__(16) unsigned char As[2][8192];  // 128 rows x 64 B
    __shared__ __align__(16) unsigned char Bs[2][8192];
    __shared__ unsigned long long redMin[128][2];
    __shared__ float redMax[128][2];

    const int t    = threadIdx.x;
    const int w    = t >> 6, lane = t & 63;
    const int wm   = w >> 1, wn = w & 1;     // 64x64 quadrant per wave
    const int q4   = lane >> 4, c15 = lane & 15;
    const int i0   = ti * 128, j0 = tj * 128;

    // staging decode: 1 KB per GLDS instr = 16 rows x 64 B.
    // lane -> row-in-instr sr = lane>>2, stored slot = lane&3,
    // global chunk c = (lane&3) ^ (sr&3)
    const int sr = lane >> 2;
    const int sc = (lane & 3) ^ (sr & 3);

    const unsigned char* gA[2]; const unsigned char* gB[2];
    int eoff[2];
    #pragma unroll
    for (int q = 0; q < 2; q++) {
        int e   = w * 2 + q;                 // staging instruction 0..7
        int row = e * 16 + sr;
        gA[q]   = xq + (size_t)(i0 + row) * D_DIM + sc * 16;
        gB[q]   = xq + (size_t)(j0 + row) * D_DIM + sc * 16;
        eoff[q] = e * 1024;                  // wave-uniform LDS base
    }

    // fragment offsets: row r = st*16+c15 (r&3 == c15&3), byte b = kk*32+q4*8
    // slot sl = kk*2+(q4>>1), stored = sl^(r&3), +8 if q4 odd
    int foff[4][2];
    #pragma unroll
    for (int st = 0; st < 4; st++)
        #pragma unroll
        for (int kk = 0; kk < 2; kk++)
            foff[st][kk] = (st * 16 + c15) * 64 +
                           ((((kk << 1) | (q4 >> 1)) ^ (c15 & 3)) << 4) +
                           ((q4 & 1) << 3);

    floatx4 acc[4][4];
    #pragma unroll
    for (int m = 0; m < 4; m++)
        #pragma unroll
        for (int n = 0; n < 4; n++)
            acc[m][n] = (floatx4){0.f, 0.f, 0.f, 0.f};

    // prologue: chunk 0 into buffer 0
    #pragma unroll
    for (int q = 0; q < 2; q++) {
        GLDS(gA[q], &As[0][eoff[q]]);
        GLDS(gB[q], &Bs[0][eoff[q]]);
    }

    for (int it = 0; it < 16; it++) {        // K = 1024, BK = 64
        __syncthreads();                     // drains chunk `it` (issued it-1)
        if (it < 15) {
            const int nb = (it + 1) & 1;
            #pragma unroll
            for (int q = 0; q < 2; q++) {
                GLDS(gA[q] + (it + 1) * 64, &As[nb][eoff[q]]);
                GLDS(gB[q] + (it + 1) * 64, &Bs[nb][eoff[q]]);
            }
        }
        const unsigned char* Ac = As[it & 1];
        const unsigned char* Bc = Bs[it & 1];
        #pragma unroll
        for (int kk = 0; kk < 2; kk++) {
            long long af[4], bfr[4];
            #pragma unroll
            for (int st = 0; st < 4; st++) {
                af[st]  = *(const long long*)(Ac + (wm * 64) * 64 + foff[st][kk]);
                bfr[st] = *(const long long*)(Bc + (wn * 64) * 64 + foff[st][kk]);
            }
            #pragma unroll
            for (int m = 0; m < 4; m++)
                #pragma unroll
                for (int n = 0; n < 4; n++)
                    acc[m][n] = __builtin_amdgcn_mfma_f32_16x16x32_fp8_fp8(
                        af[m], bfr[n], acc[m][n], 0, 0, 0);
        }
    }

    // epilogue: d = sqrt(ni + nj - 2*dot), strictly j < i; row min-pack + max
    float nj[4];
    #pragma unroll
    for (int st = 0; st < 4; st++) nj[st] = norms[j0 + wn * 64 + st * 16 + c15];

    #pragma unroll
    for (int st_m = 0; st_m < 4; st_m++) {
        #pragma unroll
        for (int r = 0; r < 4; r++) {
            int i_loc = wm * 64 + st_m * 16 + q4 * 4 + r;
            int gi    = i0 + i_loc;
            float ni  = norms[gi];
            unsigned long long mp = 0xFFFFFFFFFFFFFFFFull;
            float mx = -INF_F;
            #pragma unroll
            for (int st_n = 0; st_n < 4; st_n++) {
                int gj = j0 + wn * 64 + st_n * 16 + c15;
                if (gj < gi) {
                    float dot = acc[st_m][st_n][r];
                    float d   = sqrtf(fmaxf(ni + nj[st_n] - 2.f * dot, 0.f));
                    unsigned long long p =
                        ((unsigned long long)__float_as_uint(d) << 32) | (unsigned)gj;
                    if (p < mp) mp = p;
                    mx = fmaxf(mx, d);
                }
            }
            #pragma unroll
            for (int off = 1; off < 16; off <<= 1) {
                unsigned long long op = __shfl_xor(mp, off, 64);
                if (op < mp) mp = op;
                float om = __shfl_xor(mx, off, 64);
                mx = fmaxf(mx, om);
            }
            if (c15 == 0) { redMin[i_loc][wn] = mp; redMax[i_loc][wn] = mx; }
        }
    }
    __syncthreads();
    if (t < 128) {
        unsigned long long mp = redMin[t][0];
        if (redMin[t][1] < mp) mp = redMin[t][1];
        float mx = fmaxf(redMax[t][0], redMax[t][1]);
        if (mp != 0xFFFFFFFFFFFFFFFFull) {
            atomicMin(&minpack[i0 + t], mp);
            atomicMax(&maxbits[i0 + t], __float_as_uint(mx));
        }
    }
}

// Fused: verify all-insert (prefix min/max scan), fast-path outputs, exact
// sequential continuation only if verification failed. One block, 1024 threads.
__global__ __launch_bounds__(1024)
void k_tail(const unsigned long long* __restrict__ minpack,
            const unsigned int* __restrict__ maxbits,
            const float* __restrict__ x, const float* __restrict__ norms,
            const int* __restrict__ labels, int* __restrict__ ref_idx,
            float* __restrict__ out) {
    const int t = threadIdx.x;
    float m[4], M[4];
    #pragma unroll
    for (int q = 0; q < 4; q++) {
        int i = t * 4 + q;
        unsigned long long p = minpack[i];
        float dmin = (p == 0xFFFFFFFFFFFFFFFFull)
                       ? INF_F : __uint_as_float((unsigned)(p >> 32));
        m[q] = (i == 0) ? INF_F : dmin;
        M[q] = (i == 0) ? -INF_F : __uint_as_float(maxbits[i]);
    }
    float pmin[4], pmax[4];
    pmin[0] = m[0]; pmax[0] = M[0];
    #pragma unroll
    for (int q = 1; q < 4; q++) {
        pmin[q] = fminf(pmin[q - 1], m[q]);
        pmax[q] = fmaxf(pmax[q - 1], M[q]);
    }
    __shared__ float smin[1024], smax[1024];
    smin[t] = pmin[3]; smax[t] = pmax[3];
    __syncthreads();
    for (int off = 1; off < 1024; off <<= 1) {
        float a = (t >= off) ? smin[t - off] : INF_F;
        float b = (t >= off) ? smax[t - off] : -INF_F;
        __syncthreads();
        smin[t] = fminf(smin[t], a);
        smax[t] = fmaxf(smax[t], b);
        __syncthreads();
    }
    float exMin = (t > 0) ? smin[t - 1] : INF_F;
    float exMax = (t > 0) ? smax[t - 1] : -INF_F;

    int viol = B_N;
    #pragma unroll
    for (int q = 0; q < 4; q++) {
        int i = t * 4 + q;
        if (i >= 1) {
            float pm = (q == 0) ? exMin : fminf(exMin, pmin[q - 1]);
            float pM = (q == 0) ? exMax : fmaxf(exMax, pmax[q - 1]);
            float R  = (i == 1) ? 1.0f : (pm + pM) / 3.0f;
            if (!(m[q] > R) && i < viol) viol = i;
        }
    }
    __shared__ int sv[1024];
    sv[t] = viol;
    __syncthreads();
    for (int off = 512; off; off >>= 1) {
        if (t < off) sv[t] = min(sv[t], sv[t + off]);
        __syncthreads();
    }
    const int s_star = sv[0];

    for (int i = t; i < s_star; i += 1024) out[i] = (float)labels[i];

    __shared__ float s_state[3];
    __shared__ int s_n;
    if (s_star < B_N && t == (s_star >> 2)) {
        int q = s_star & 3;
        float pm = (q == 0) ? exMin : fminf(exMin, pmin[q - 1]);
        float pM = (q == 0) ? exMax : fmaxf(exMax, pmax[q - 1]);
        float md = fminf(pm, m[q]);
        float Md = fmaxf(pM, M[q]);
        s_state[0] = md; s_state[1] = Md; s_state[2] = (md + Md) / 3.0f;
        s_n = s_star;
        unsigned long long p = minpack[s_star];
        int j = (int)(unsigned)(p & 0xFFFFFFFFu);
        out[s_star] = (float)labels[j];
    }
    if (s_star >= B_N) return;

    for (int s = t; s < s_star; s += 1024) ref_idx[s] = s;
    __syncthreads();

    __shared__ unsigned long long redp[1024];
    __shared__ float redm[1024];
    for (int i = s_star + 1; i < B_N; i++) {
        int n = s_n;
        const float* xi = x + (size_t)i * D_DIM;
        float ni = norms[i];
        unsigned long long mp = 0xFFFFFFFFFFFFFFFFull;
        float mx = -INF_F;
        for (int slot = t; slot < n; slot += 1024) {
            int j = ref_idx[slot];
            const float* xj = x + (size_t)j * D_DIM;
            float dot = 0.f;
            for (int k = 0; k < D_DIM; k++) dot = fmaf(xi[k], xj[k], dot);
            float d = sqrtf(fmaxf(ni + norms[j] - 2.f * dot, 0.f));
            unsigned long long p =
                ((unsigned long long)__float_as_uint(d) << 32) | (unsigned)slot;
            if (p < mp) mp = p;
            mx = fmaxf(mx, d);
        }
        redp[t] = mp; redm[t] = mx;
        __syncthreads();
        for (int off = 512; off; off >>= 1) {
            if (t < off) {
                if (redp[t + off] < redp[t]) redp[t] = redp[t + off];
                redm[t] = fmaxf(redm[t], redm[t + off]);
            }
            __syncthreads();
        }
        if (t == 0) {
            unsigned long long p = redp[0];
            float min_act = __uint_as_float((unsigned)(p >> 32));
            int minslot   = (int)(unsigned)(p & 0xFFFFFFFFu);
            float max_act = redm[0];
            bool insert = (min_act > s_state[2]);
            int pred;
            if (insert) {
                ref_idx[n] = i;
                s_n = n + 1;
                pred = (min_act <= 0.0f) ? labels[ref_idx[minslot]] : labels[i];
            } else {
                pred = labels[ref_idx[minslot]];
            }
            float md = fminf(s_state[0], min_act);
            float Md = fmaxf(s_state[1], max_act);
            s_state[0] = md; s_state[1] = Md; s_state[2] = (md + Md) / 3.0f;
            out[i] = (float)pred;
        }
        __syncthreads();
    }
}

extern "C" void kernel_launch(void* const* d_in, const int* in_sizes, int n_in,
                              void* d_out, int out_size, void* d_ws, size_t ws_size,
                              hipStream_t stream) {
    const float* x      = (const float*)d_in[0];
    const int*   labels = (const int*)d_in[1];
    float*       out    = (float*)d_out;
    char* ws = (char*)d_ws;
    unsigned long long* minpack = (unsigned long long*)ws;
    unsigned int*       maxbits = (unsigned int*)(ws + 32768);
    float*              norms   = (float*)(ws + 49152);
    int*                ref_idx = (int*)(ws + 65600);
    unsigned char*      xq      = (unsigned char*)(ws + XQ_OFF);

    k_prep<<<B_N, 256, 0, stream>>>(x, xq, norms, minpack, maxbits);
    const int ntiles  = B_N / 128;                       // 32
    const int nblocks = ntiles * (ntiles + 1) / 2;       // 528
    k_pass1_fp8<<<nblocks, 256, 0, stream>>>(xq, norms, minpack, maxbits);
    k_tail<<<1, 1024, 0, stream>>>(minpack, maxbits, x, norms, labels, ref_idx, out);
}